// Round 14
// baseline (75.505 us; speedup 1.0000x reference)
//
#include <hip/hip_runtime.h>
#include <math.h>

#define NB 4
#define FRAMES 400
#define NBINS 129
#define HOP 240
#define T_LEN (FRAMES * HOP)   // 96000
#define KLEN 256               // FIR length = 2*(NBINS-1)
#define NGEN (NB * FRAMES)     // 1600 gen blocks
#define NFIRX 188              // fir blocks per batch: ceil(96000/512)
#define NFIR (NFIRX * NB)      // 752 fir blocks

#define REC_C { const float cn_ = fmaf(a2, cm, -cm1); cm1 = cm; cm = cn_; }
#define REC_S { const float sn_ = fmaf(a2, sm, -sm1); sm1 = sm; sm = sn_; }

// ---------------------------------------------------------------------------
// Fused single-dispatch producer/consumer.
//  blocks [0,1600):    gen — R13-proven k-split minimum-phase FIR builder
//                      (256 thr: n=tid&127, h=tid>>7 accumulates half the
//                      DFT sums; Chebyshev recurrences, HW trig in revs).
//                      Ends: __syncthreads -> threadfence -> flag[bf]=1.
//  blocks [1600,2352): fir — R10-proven time-varying FIR (2 outputs/thread,
//                      (kL,kH)-interleaved kp, b64 x + register carry).
//                      Stages x first, then tid0 spins on the 5 row flags
//                      (s_sleep), threadfence, barrier, stage kp, compute.
// Deadlock-free by capacity: worst-case all 752 fir blocks resident+spinning
// use <=12 waves + 34KB LDS per CU, leaving >=20 waves + >=120KB -> >=5 gen
// blocks per CU can always be resident. No dispatch-order assumption (G16).
// Flags zeroed each call via hipMemsetAsync -> no cross-replay staleness.
// ---------------------------------------------------------------------------
__global__ __launch_bounds__(256) void ltv_fused(const float* __restrict__ ex,
                                                 const float* __restrict__ log_mag,
                                                 float* __restrict__ kern,
                                                 int* __restrict__ flags,
                                                 float* __restrict__ out) {
    const int bid = blockIdx.x;
    const int tid = threadIdx.x;

    __shared__ __align__(16) float smem[2832];   // union: gen 1416 / fir 2832 floats

    if (bid < NGEN) {
        // =================== GEN block (R13 verbatim math) ===================
        const int bf = bid;            // b*FRAMES + f
        const int n  = tid & 127;
        const int h  = tid >> 7;       // k/m half: [64h, 64h+64)

        float*  full = smem;                       // [0,132)
        float*  pg0  = smem + 136;                 // pg[2][128]
        float*  pm0  = smem + 392;                 // pm[2][128]
        float2* crci = (float2*)(smem + 648);      // [128]
        float*  pe0  = smem + 904;                 // pe[2][128]
        float*  po0  = smem + 1160;                // po[2][128]

        const float* lm = log_mag + bf * NBINS;
        if (tid < NBINS) full[tid] = lm[tid];

        const float rev_n = (float)n * (1.0f / 256.0f);
        const float ca = __builtin_amdgcn_cosf(rev_n);
        const float sa = __builtin_amdgcn_sinf(rev_n);
        const float a2  = 2.0f * ca;
        const float sgn = (n & 1) ? -1.0f : 1.0f;

        float cm0, cm1_0, sm0, sm1_0;
        if (h == 0) {
            cm0 = 1.0f;  cm1_0 = ca;
            sm0 = 0.0f;  sm1_0 = -sa;
        } else {
            const float r64 = (float)((64 * n) & 255) * (1.0f / 256.0f);  // exact
            const float r63 = (float)((63 * n) & 255) * (1.0f / 256.0f);
            cm0   = __builtin_amdgcn_cosf(r64);
            sm0   = __builtin_amdgcn_sinf(r64);
            cm1_0 = __builtin_amdgcn_cosf(r63);
            sm1_0 = __builtin_amdgcn_sinf(r63);
        }
        __syncthreads();

        const float full0   = full[0];
        const float full128 = full[128];

        // loop1 (half): pg[h][n]
        {
            const float4* f4p = (const float4*)full;
            float cm1 = cm1_0, cm = cm0, acc = 0.0f;
#pragma unroll 8
            for (int u = 16 * h; u < 16 * h + 16; ++u) {
                const float4 f4 = f4p[u];
                acc = fmaf(f4.x, cm, acc); REC_C;
                acc = fmaf(f4.y, cm, acc); REC_C;
                acc = fmaf(f4.z, cm, acc); REC_C;
                acc = fmaf(f4.w, cm, acc); REC_C;
            }
            const float share = h ? (sgn * full128) : (-full0);
            pg0[h * 128 + n] = acc * (1.0f / 64.0f) + share * (1.0f / 128.0f);
        }
        __syncthreads();

        // loop2 (half): pm[h][n]
        {
            const float4* p0 = (const float4*)pg0;
            const float4* p1 = (const float4*)(pg0 + 128);
            float sm1 = sm1_0, sm = sm0, acc = 0.0f;
#pragma unroll 8
            for (int u = 16 * h; u < 16 * h + 16; ++u) {
                const float4 a4 = p0[u];
                const float4 b4 = p1[u];
                acc = fmaf(a4.x + b4.x, sm, acc); REC_S;
                acc = fmaf(a4.y + b4.y, sm, acc); REC_S;
                acc = fmaf(a4.z + b4.z, sm, acc); REC_S;
                acc = fmaf(a4.w + b4.w, sm, acc); REC_S;
            }
            pm0[h * 128 + n] = acc;
        }
        __syncthreads();

        // crci[n] (h=0 threads)
        if (h == 0) {
            const float mp = -(pm0[n] + pm0[128 + n]);
            const float e  = __builtin_amdgcn_exp2f(full[n] * 1.4426950408889634f);
            float rev = mp * 0.15915494309189535f;
            rev = rev - floorf(rev);
            const float smp  = __builtin_amdgcn_sinf(rev);
            const float cmp_ = __builtin_amdgcn_cosf(rev);
            const float sc = (n == 0) ? 1.0f : 2.0f;
            crci[n] = make_float2(sc * e * cmp_, sc * e * smp);
        }
        __syncthreads();

        // loop3 (half): pe/po
        {
            const float4* cc4 = (const float4*)crci;
            float cm1 = cm1_0, cm = cm0;
            float sm1 = sm1_0, sm = sm0;
            float accE = 0.0f, accO = 0.0f;
#pragma unroll 8
            for (int u = 32 * h; u < 32 * h + 32; ++u) {
                const float4 q = cc4[u];
                accE = fmaf(q.x, cm, accE); accE = fmaf(-q.y, sm, accE);
                REC_C; REC_S;
                accO = fmaf(q.z, cm, accO); accO = fmaf(-q.w, sm, accO);
                REC_C; REC_S;
            }
            pe0[h * 128 + n] = accE;
            po0[h * 128 + n] = accO;
        }
        __syncthreads();

        // epilogue: combine, window, store row
        if (h == 0) {
            const float accE = pe0[n] + pe0[128 + n];
            const float accO = po0[n] + po0[128 + n];
            const float e128 = __builtin_amdgcn_exp2f(full128 * 1.4426950408889634f);
            const float base = sgn * e128;
            const float s = 1.0f / 256.0f;
            kern[bf * KLEN + n]       = (accE + accO + base) * s;
            kern[bf * KLEN + n + 128] = (accE - accO + base) * s * (0.5f + 0.5f * ca);
        }
        __syncthreads();                 // all row stores drained (vmcnt before barrier)
        if (tid == 0) {
            __threadfence();             // publish to agent scope
            __hip_atomic_store(&flags[bf], 1, __ATOMIC_RELAXED, __HIP_MEMORY_SCOPE_AGENT);
        }
        return;
    }

    // ===================== FIR block (R10 verbatim math) =====================
    const int idx = bid - NGEN;
    const int b   = idx / NFIRX;
    const int t0  = (idx % NFIRX) * 512;

    float*  xs = smem;                         // [0,768)
    float2* kp = (float2*)(smem + 768);        // [4][258]

    for (int i = tid; i < 768; i += 256) {
        const int t = t0 - 255 + i;
        xs[i] = (t >= 0 && t < T_LEN) ? ex[b * T_LEN + t] : 0.0f;
    }

    float src0 = ((float)t0 + 0.5f) * (1.0f / HOP) - 0.5f;
    src0 = fminf(fmaxf(src0, 0.0f), (float)(FRAMES - 1));
    const int f0 = (int)src0;

    // wait for the 5 (clamped) producer rows of this batch
    if (tid == 0) {
#pragma unroll
        for (int d = 0; d < 5; ++d) {
            const int row = b * FRAMES + min(f0 + d, FRAMES - 1);
            while (__hip_atomic_load(&flags[row], __ATOMIC_RELAXED,
                                     __HIP_MEMORY_SCOPE_AGENT) == 0)
                __builtin_amdgcn_s_sleep(2);
        }
        __threadfence();                 // acquire: invalidate stale cache lines
    }
    __syncthreads();                     // also covers xs staging

    const float* kb = kern + b * FRAMES * KLEN;
    for (int i = tid; i < 4 * KLEN; i += 256) {
        const int q = i >> 8;
        const int j = i & 255;
        const int fl = min(f0 + q,     FRAMES - 1);
        const int fh = min(f0 + q + 1, FRAMES - 1);
        kp[q * 258 + j] = make_float2(kb[fl * KLEN + j], kb[fh * KLEN + j]);
    }
    __syncthreads();

    const int te = t0 + 2 * tid;
    float se = ((float)te + 0.5f) * (1.0f / HOP) - 0.5f;
    se = fminf(fmaxf(se, 0.0f), (float)(FRAMES - 1));
    float so = ((float)te + 1.5f) * (1.0f / HOP) - 0.5f;
    so = fminf(fmaxf(so, 0.0f), (float)(FRAMES - 1));
    const int   lo = (int)se;            // == lo(te+1), boundary-safe by parity
    const float we = se - (float)lo;
    const float wo = so - (float)lo;

    const float4* kq4 = (const float4*)&kp[(lo - f0) * 258];

    const int base = 2 * tid;            // xs index of x[te] is base+255
    float carry = xs[base + 256];        // x[te+1]
    float aeL = 0.0f, aeH = 0.0f, aoL = 0.0f, aoH = 0.0f;
#pragma unroll 8
    for (int u = 0; u < 128; ++u) {
        const float2 v  = *(const float2*)&xs[base + 254 - 2 * u];
        const float4 k4 = kq4[u];
        aeL = fmaf(v.y,   k4.x, aeL);  aeH = fmaf(v.y,   k4.y, aeH);
        aoL = fmaf(carry, k4.x, aoL);  aoH = fmaf(carry, k4.y, aoH);
        aeL = fmaf(v.x,   k4.z, aeL);  aeH = fmaf(v.x,   k4.w, aeH);
        aoL = fmaf(v.y,   k4.z, aoL);  aoH = fmaf(v.y,   k4.w, aoH);
        carry = v.x;
    }

    if (te < T_LEN)     out[b * T_LEN + te]     = (1.0f - we) * aeL + we * aeH;
    if (te + 1 < T_LEN) out[b * T_LEN + te + 1] = (1.0f - wo) * aoL + wo * aoH;
}

// ---------------------------------------------------------------------------
extern "C" void kernel_launch(void* const* d_in, const int* in_sizes, int n_in,
                              void* d_out, int out_size, void* d_ws, size_t ws_size,
                              hipStream_t stream) {
    const float* ex      = (const float*)d_in[0];
    const float* log_mag = (const float*)d_in[1];
    float* kern  = (float*)d_ws;                       // 1600*256 floats
    int*   flags = (int*)((char*)d_ws + NGEN * KLEN * sizeof(float));
    float* out   = (float*)d_out;

    hipMemsetAsync(flags, 0, NGEN * sizeof(int), stream);   // reset every call

    ltv_fused<<<NGEN + NFIR, 256, 0, stream>>>(ex, log_mag, kern, flags, out);
}

// Round 15
// 24.402 us; speedup vs baseline: 3.0942x; 3.0942x over previous
//
#include <hip/hip_runtime.h>
#include <math.h>

#define NB 4
#define FRAMES 400
#define NBINS 129
#define HOP 240
#define T_LEN (FRAMES * HOP)   // 96000
#define KLEN 256               // FIR length = 2*(NBINS-1)

#define REC_C { const float cn_ = fmaf(a2, cm, -cm1); cm1 = cm; cm = cn_; }
#define REC_S { const float sn_ = fmaf(a2, sm, -sm1); sm1 = sm; sm = sn_; }

// ---------------------------------------------------------------------------
// Kernel 1 (R13 — best measured): K-SPLIT gen. 256 threads: thread
// (n = tid&127, h = tid>>7) accumulates the h-th HALF (64 terms) of each DFT
// sum for outputs (ker[n], ker[n+128]). Chebyshev recurrences seeded
// mid-stream at m0 = 64h via exact integer-argument HW sincos. Halves combine
// through LDS partials. HW trig in revolutions.
// ---------------------------------------------------------------------------
__global__ __launch_bounds__(256) void gen_fir(const float* __restrict__ log_mag,
                                               float* __restrict__ kern) {
    const int bf  = blockIdx.x;    // 0..NB*FRAMES-1
    const int tid = threadIdx.x;   // 0..255
    const int n   = tid & 127;
    const int h   = tid >> 7;      // k/m half: [64h, 64h+64)

    __shared__ __align__(16) float  full[132];     // lm[0..128]
    __shared__ __align__(16) float  pg[2][128];    // loop1 partials (pre-scaled)
    __shared__ __align__(16) float  pm[2][128];    // loop2 partials
    __shared__ __align__(16) float2 crci[128];     // (wC[k], wS[k])
    __shared__ __align__(16) float  pe[2][128];    // loop3 accE partials
    __shared__ __align__(16) float  po[2][128];    // loop3 accO partials

    const float* lm = log_mag + bf * NBINS;
    if (tid < NBINS) full[tid] = lm[tid];

    const float rev_n = (float)n * (1.0f / 256.0f);
    const float ca = __builtin_amdgcn_cosf(rev_n);   // cos(2*pi*n/256)
    const float sa = __builtin_amdgcn_sinf(rev_n);
    const float a2  = 2.0f * ca;
    const float sgn = (n & 1) ? -1.0f : 1.0f;        // (-1)^n

    // recurrence seeds at m0 = 64h
    float cm0, cm1_0, sm0, sm1_0;
    if (h == 0) {
        cm0 = 1.0f;  cm1_0 = ca;    // cos(0), cos(-na)
        sm0 = 0.0f;  sm1_0 = -sa;   // sin(0), sin(-na)
    } else {
        const float r64 = (float)((64 * n) & 255) * (1.0f / 256.0f);  // exact
        const float r63 = (float)((63 * n) & 255) * (1.0f / 256.0f);
        cm0   = __builtin_amdgcn_cosf(r64);
        sm0   = __builtin_amdgcn_sinf(r64);
        cm1_0 = __builtin_amdgcn_cosf(r63);
        sm1_0 = __builtin_amdgcn_sinf(r63);
    }
    __syncthreads();

    const float full0   = full[0];
    const float full128 = full[128];

    // ---- loop1 (half): pg[h][n];  g[n] = pg[0][n] + pg[1][n]
    {
        const float4* f4p = (const float4*)full;
        float cm1 = cm1_0, cm = cm0, acc = 0.0f;
#pragma unroll 8
        for (int u = 16 * h; u < 16 * h + 16; ++u) {
            const float4 f4 = f4p[u];
            acc = fmaf(f4.x, cm, acc); REC_C;
            acc = fmaf(f4.y, cm, acc); REC_C;
            acc = fmaf(f4.z, cm, acc); REC_C;
            acc = fmaf(f4.w, cm, acc); REC_C;
        }
        const float share = h ? (sgn * full128) : (-full0);
        pg[h][n] = acc * (1.0f / 64.0f) + share * (1.0f / 128.0f);
    }
    __syncthreads();

    // ---- loop2 (half): pm[h][n], g folded inline
    {
        const float4* p0 = (const float4*)pg[0];
        const float4* p1 = (const float4*)pg[1];
        float sm1 = sm1_0, sm = sm0, acc = 0.0f;
#pragma unroll 8
        for (int u = 16 * h; u < 16 * h + 16; ++u) {
            const float4 a4 = p0[u];
            const float4 b4 = p1[u];
            acc = fmaf(a4.x + b4.x, sm, acc); REC_S;
            acc = fmaf(a4.y + b4.y, sm, acc); REC_S;
            acc = fmaf(a4.z + b4.z, sm, acc); REC_S;
            acc = fmaf(a4.w + b4.w, sm, acc); REC_S;
        }
        pm[h][n] = acc;
    }
    __syncthreads();

    // ---- crci[n] from mp[n] = -(pm[0][n]+pm[1][n])   (h=0 threads)
    if (h == 0) {
        const float mp = -(pm[0][n] + pm[1][n]);
        const float e  = __builtin_amdgcn_exp2f(full[n] * 1.4426950408889634f);
        float rev = mp * 0.15915494309189535f;       // mp / (2*pi)
        rev = rev - floorf(rev);                     // fract reduction
        const float smp  = __builtin_amdgcn_sinf(rev);
        const float cmp_ = __builtin_amdgcn_cosf(rev);
        const float sc = (n == 0) ? 1.0f : 2.0f;
        crci[n] = make_float2(sc * e * cmp_, sc * e * smp);
    }
    __syncthreads();

    // ---- loop3 (half): accE (even k), accO (odd k) over k in [64h, 64h+64)
    {
        const float4* cc4 = (const float4*)crci;
        float cm1 = cm1_0, cm = cm0;
        float sm1 = sm1_0, sm = sm0;
        float accE = 0.0f, accO = 0.0f;
#pragma unroll 8
        for (int u = 32 * h; u < 32 * h + 32; ++u) {
            const float4 q = cc4[u];   // C'[2u], S'[2u], C'[2u+1], S'[2u+1]
            accE = fmaf(q.x, cm, accE); accE = fmaf(-q.y, sm, accE);
            REC_C; REC_S;
            accO = fmaf(q.z, cm, accO); accO = fmaf(-q.w, sm, accO);
            REC_C; REC_S;
        }
        pe[h][n] = accE;
        po[h][n] = accO;
    }
    __syncthreads();

    // ---- epilogue (h=0 threads): combine halves, window, store
    if (h == 0) {
        const float accE = pe[0][n] + pe[1][n];
        const float accO = po[0][n] + po[1][n];
        const float e128 = __builtin_amdgcn_exp2f(full128 * 1.4426950408889634f);
        const float base = sgn * e128;
        const float s = 1.0f / 256.0f;
        kern[bf * KLEN + n]       = (accE + accO + base) * s;
        kern[bf * KLEN + n + 128] = (accE - accO + base) * s * (0.5f + 0.5f * ca);
    }
}

// ---------------------------------------------------------------------------
// Kernel 2 (R10 verbatim — best measured fir): 256 threads, 2 adjacent
// outputs per thread; kp (kL,kH) interleaved so one ds_read_b128 = 2 taps of
// both kernels; x via b64 + register carry; 8 independent accumulator chains.
// ---------------------------------------------------------------------------
__global__ __launch_bounds__(256) void fir_apply(const float* __restrict__ ex,
                                                 const float* __restrict__ kern,
                                                 float* __restrict__ out) {
    const int b   = blockIdx.y;
    const int t0  = blockIdx.x * 512;
    const int tid = threadIdx.x;

    __shared__ __align__(16) float  xs[768];        // x[t0-255 .. t0+256]
    __shared__ __align__(16) float2 kp[4][258];     // (kerLo[j], kerHi[j]) per q; +2 pad

    for (int i = tid; i < 768; i += 256) {
        const int t = t0 - 255 + i;
        xs[i] = (t >= 0 && t < T_LEN) ? ex[b * T_LEN + t] : 0.0f;
    }

    // frames needed by this block: f0 .. f0+3 (clamped)
    float src0 = ((float)t0 + 0.5f) * (1.0f / HOP) - 0.5f;
    src0 = fminf(fmaxf(src0, 0.0f), (float)(FRAMES - 1));
    const int f0 = (int)src0;
    const float* kb = kern + b * FRAMES * KLEN;
    for (int i = tid; i < 4 * KLEN; i += 256) {
        const int q = i >> 8;
        const int j = i & 255;
        const int fl = min(f0 + q,     FRAMES - 1);
        const int fh = min(f0 + q + 1, FRAMES - 1);
        kp[q][j] = make_float2(kb[fl * KLEN + j], kb[fh * KLEN + j]);
    }
    __syncthreads();

    const int te = t0 + 2 * tid;
    float se = ((float)te + 0.5f) * (1.0f / HOP) - 0.5f;
    se = fminf(fmaxf(se, 0.0f), (float)(FRAMES - 1));
    float so = ((float)te + 1.5f) * (1.0f / HOP) - 0.5f;
    so = fminf(fmaxf(so, 0.0f), (float)(FRAMES - 1));
    const int   lo = (int)se;           // == lo(te+1), boundary-safe by parity
    const float we = se - (float)lo;
    const float wo = so - (float)lo;

    const float4* kq4 = (const float4*)&kp[lo - f0][0];   // (kL[2u],kH[2u],kL[2u+1],kH[2u+1])

    const int base = 2 * tid;           // xs index of x[te] is base+255
    float carry = xs[base + 256];       // x[te+1]
    float aeL = 0.0f, aeH = 0.0f, aoL = 0.0f, aoH = 0.0f;
#pragma unroll 8
    for (int u = 0; u < 128; ++u) {
        const float2 v  = *(const float2*)&xs[base + 254 - 2 * u];  // (x[te-2u-1], x[te-2u])
        const float4 k4 = kq4[u];
        aeL = fmaf(v.y,   k4.x, aeL);  aeH = fmaf(v.y,   k4.y, aeH);   // out e, j=2u
        aoL = fmaf(carry, k4.x, aoL);  aoH = fmaf(carry, k4.y, aoH);   // out o, j=2u
        aeL = fmaf(v.x,   k4.z, aeL);  aeH = fmaf(v.x,   k4.w, aeH);   // out e, j=2u+1
        aoL = fmaf(v.y,   k4.z, aoL);  aoH = fmaf(v.y,   k4.w, aoH);   // out o, j=2u+1
        carry = v.x;
    }

    if (te < T_LEN)     out[b * T_LEN + te]     = (1.0f - we) * aeL + we * aeH;
    if (te + 1 < T_LEN) out[b * T_LEN + te + 1] = (1.0f - wo) * aoL + wo * aoH;
}

// ---------------------------------------------------------------------------
extern "C" void kernel_launch(void* const* d_in, const int* in_sizes, int n_in,
                              void* d_out, int out_size, void* d_ws, size_t ws_size,
                              hipStream_t stream) {
    const float* ex      = (const float*)d_in[0];
    const float* log_mag = (const float*)d_in[1];
    float* kern = (float*)d_ws;          // NB*FRAMES*KLEN floats = 1.6 MB
    float* out  = (float*)d_out;

    gen_fir<<<NB * FRAMES, 256, 0, stream>>>(log_mag, kern);

    dim3 grid((T_LEN + 511) / 512, NB);
    fir_apply<<<grid, 256, 0, stream>>>(ex, kern, out);
}